// Round 1
// baseline (176.885 us; speedup 1.0000x reference)
//
#include <hip/hip_runtime.h>

// SSKernelNPLR: H=256 SSM heads, N=32 (M=64 conj-extended), R=1, CH=1, L=8192.
// Stage A (per-h block): build dA = diag(DcEc) - (DcPc2)(Qc2+s)^T  [exact R=1
//   collapse of the reference einsums], 13 LDS squarings -> dA^8192, then
//   C_t = (C_ - dA_L^T C_)[:32]  -> workspace.
// Stage B (per-h block): Cauchy matvec over 4097 FFT nodes (z = 2i tan(pi j/L)),
//   rank-1 Woodbury, *(1+i tan), then irfft via real-packing + 12-stage
//   Stockham radix-2 inverse FFT (length 4096) in LDS.

#define HH 256
#define NN 32
#define LL 8192
#define LF 4097   // LL/2 + 1
#define MF 4096   // LL/2

typedef float2 c32;

__device__ __forceinline__ c32 cmul(c32 a, c32 b){ return make_float2(a.x*b.x - a.y*b.y, a.x*b.y + a.y*b.x); }
__device__ __forceinline__ c32 cadd(c32 a, c32 b){ return make_float2(a.x+b.x, a.y+b.y); }
__device__ __forceinline__ c32 csub(c32 a, c32 b){ return make_float2(a.x-b.x, a.y-b.y); }
__device__ __forceinline__ c32 cconjf(c32 a){ return make_float2(a.x, -a.y); }
__device__ __forceinline__ void cmac(c32& acc, c32 a, c32 b){
  acc.x = fmaf(a.x, b.x, fmaf(-a.y, b.y, acc.x));
  acc.y = fmaf(a.x, b.y, fmaf(a.y, b.x, acc.y));
}

// ---------------- Kernel A: dA^L and C_t ----------------
__global__ __launch_bounds__(256)
void ssk_setup(const float* __restrict__ log_dt, const float* __restrict__ invwr,
               const float* __restrict__ wim, const float* __restrict__ Pin,
               const float* __restrict__ Cin, c32* __restrict__ Ct_ws)
{
  // stride 65 pad: column read bank = (2r+2k)%32 -> conflict-free
  __shared__ c32 bufA[64*65];
  __shared__ c32 bufB[64*65];
  __shared__ c32 uvec[64], dvec[64], pvec[64], cful[64];
  const int h = blockIdx.x;
  const int tid = threadIdx.x;

  if (tid < 64) {  // wave 0 does the scalar setup; m = tid, conj half for m>=32
    const int n = tid & 31;
    const bool cj = tid >= 32;
    const float dt = expf(log_dt[h]);
    float wr = -expf(invwr[h*NN + n]);
    float wi = wim[h*NN + n];
    if (cj) wi = -wi;
    const float tdt = 2.0f / dt;
    // D = 1/(2/dt - w); E = 2/dt + w   (on conj-extended w)
    float dr = tdt - wr, di = -wi;
    float invd = 1.0f / (dr*dr + di*di);
    c32 D = make_float2(dr*invd, -di*invd);
    c32 E = make_float2(tdt + wr, wi);
    c32 Pf = make_float2(Pin[(h*NN+n)*2], Pin[(h*NN+n)*2+1]);
    if (cj) Pf.y = -Pf.y;
    c32 Cf = make_float2(Cin[(h*NN+n)*2], Cin[(h*NN+n)*2+1]);
    if (cj) Cf.y = -Cf.y;
    // Rm = 1 + sum_{m=0}^{63} |Pf|^2 Re(D)   (= 1 + 2*sum_n, via conj pairs)
    float rm = (Pf.x*Pf.x + Pf.y*Pf.y) * D.x;
    #pragma unroll
    for (int off = 32; off >= 1; off >>= 1) rm += __shfl_xor(rm, off, 64);
    rm += 1.0f;
    // Rc = conj(Pf)*D / Rm  (conj-extension-consistent)
    c32 Rc = cmul(cconjf(Pf), D);
    float invrm = 1.0f / rm;
    Rc.x *= invrm; Rc.y *= invrm;
    // RP = sum_m Rc[m]*Pf[m]
    c32 RP = cmul(Rc, Pf);
    #pragma unroll
    for (int off = 32; off >= 1; off >>= 1) {
      RP.x += __shfl_xor(RP.x, off, 64);
      RP.y += __shfl_xor(RP.y, off, 64);
    }
    c32 Q2 = cconjf(Pf);                       // Qc2[m] = conj(P_full[m])
    c32 s  = csub(cmul(Rc, E), cmul(RP, Q2));  // s[b] = Rc[b]E[b] - RP*Q2[b]
    uvec[tid] = cadd(Q2, s);                   // u = Q2 + s
    dvec[tid] = cmul(D, E);                    // diagonal term
    pvec[tid] = cmul(D, Pf);                   // rank-1 left vector
    cful[tid] = Cf;
  }
  __syncthreads();

  // build dA[r][c] = dvec[r]*delta - pvec[r]*uvec[c]; strided 4x4 tiles
  const int r0 = tid >> 4;
  const int c0 = tid & 15;
  #pragma unroll
  for (int i = 0; i < 4; i++) {
    #pragma unroll
    for (int j = 0; j < 4; j++) {
      int r = r0 + 16*i, c = c0 + 16*j;
      c32 v = cmul(pvec[r], uvec[c]);
      v.x = -v.x; v.y = -v.y;
      if (r == c) { v.x += dvec[r].x; v.y += dvec[r].y; }
      bufA[r*65 + c] = v;
    }
  }
  __syncthreads();

  // 13 squarings: dA^(2^13) = dA^8192
  c32* src = bufA;
  c32* dst = bufB;
  for (int it = 0; it < 13; it++) {
    c32 acc[4][4];
    #pragma unroll
    for (int i = 0; i < 4; i++)
      #pragma unroll
      for (int j = 0; j < 4; j++)
        acc[i][j] = make_float2(0.0f, 0.0f);
    #pragma unroll 2
    for (int k = 0; k < 64; k++) {
      c32 av[4], bv[4];
      av[0] = src[(r0     )*65 + k];
      av[1] = src[(r0 + 16)*65 + k];
      av[2] = src[(r0 + 32)*65 + k];
      av[3] = src[(r0 + 48)*65 + k];
      bv[0] = src[k*65 + c0     ];
      bv[1] = src[k*65 + c0 + 16];
      bv[2] = src[k*65 + c0 + 32];
      bv[3] = src[k*65 + c0 + 48];
      #pragma unroll
      for (int i = 0; i < 4; i++)
        #pragma unroll
        for (int j = 0; j < 4; j++)
          cmac(acc[i][j], av[i], bv[j]);
    }
    #pragma unroll
    for (int i = 0; i < 4; i++)
      #pragma unroll
      for (int j = 0; j < 4; j++)
        dst[(r0 + 16*i)*65 + (c0 + 16*j)] = acc[i][j];
    __syncthreads();        // writes visible; old src no longer read
    c32* t = src; src = dst; dst = t;
  }

  // C_t[m] = C_full[m] - sum_n dA_L[n][m] * C_full[n],  m < 32
  if (tid < 32) {
    c32 acc = make_float2(0.0f, 0.0f);
    for (int n2 = 0; n2 < 64; n2++) cmac(acc, src[n2*65 + tid], cful[n2]);
    Ct_ws[h*NN + tid] = csub(cful[tid], acc);
  }
}

// ---------------- Kernel B: Cauchy + Woodbury + irfft ----------------
__global__ __launch_bounds__(512)
void ssk_kern(const float* __restrict__ log_dt, const float* __restrict__ invwr,
              const float* __restrict__ wim, const float* __restrict__ Pin,
              const float* __restrict__ Bin, const c32* __restrict__ Ct_ws,
              c32* __restrict__ out)
{
  __shared__ c32 Xs[LF + 1];   // spectrum X[0..4096]; reused as FFT ping buffer
  __shared__ c32 Zs[MF];       // packed complex sequence / FFT pong buffer
  __shared__ c32 wdt_s[NN];
  __shared__ c32 vs[4][NN];    // v00,v01,v10,v11 per n
  const int h = blockIdx.x;
  const int tid = threadIdx.x;

  if (tid < NN) {
    const int n = tid;
    float dt = expf(log_dt[h]);
    float wr = -expf(invwr[h*NN + n]);
    float wi = wim[h*NN + n];
    wdt_s[n] = make_float2(wr*dt, wi*dt);
    c32 Bc = make_float2(Bin[(h*NN+n)*2], Bin[(h*NN+n)*2+1]);
    c32 Pc = make_float2(Pin[(h*NN+n)*2], Pin[(h*NN+n)*2+1]);
    c32 Qc = cconjf(Pc);
    c32 Ct = Ct_ws[h*NN + n];
    c32 v00 = cmul(Bc, Ct), v01 = cmul(Bc, Qc), v10 = cmul(Pc, Ct), v11 = cmul(Pc, Qc);
    vs[0][n] = make_float2(v00.x*dt, v00.y*dt);
    vs[1][n] = make_float2(v01.x*dt, v01.y*dt);
    vs[2][n] = make_float2(v10.x*dt, v10.y*dt);
    vs[3][n] = make_float2(v11.x*dt, v11.y*dt);
  }
  __syncthreads();

  // --- Cauchy sum at z_j = 2i*tan(pi j / L), incl. conjugate pairs ---
  for (int j = tid; j < LF; j += 512) {
    double phid = (double)j * (3.14159265358979323846 / 8192.0);
    float T = (float)tan(phid);          // huge-but-finite at j=4096: limit is exact
    float t2 = 2.0f * T;                 // z = i*t2
    c32 r00 = {0,0}, r01 = {0,0}, r10 = {0,0}, r11 = {0,0};
    #pragma unroll 4
    for (int n = 0; n < NN; n++) {
      c32 w = wdt_s[n];
      float nr  = -w.x;
      float d1i = t2 - w.y;              // z - w
      float d2i = t2 + w.y;              // z - conj(w)
      float inv1 = 1.0f / fmaf(nr, nr, d1i*d1i);
      float inv2 = 1.0f / fmaf(nr, nr, d2i*d2i);
      float c1x = nr*inv1, c1y = -d1i*inv1;
      float c2x = nr*inv2, c2y = -d2i*inv2;
      // v*c1 + conj(v)*c2 folded: re += vx*sx - vy*dyy ; im += vx*sy + vy*dxx
      float sx = c1x + c2x, dxx = c1x - c2x;
      float sy = c1y + c2y, dyy = c1y - c2y;
      c32 v;
      v = vs[0][n];
      r00.x = fmaf(v.x, sx, fmaf(-v.y, dyy, r00.x));
      r00.y = fmaf(v.x, sy, fmaf( v.y, dxx, r00.y));
      v = vs[1][n];
      r01.x = fmaf(v.x, sx, fmaf(-v.y, dyy, r01.x));
      r01.y = fmaf(v.x, sy, fmaf( v.y, dxx, r01.y));
      v = vs[2][n];
      r10.x = fmaf(v.x, sx, fmaf(-v.y, dyy, r10.x));
      r10.y = fmaf(v.x, sy, fmaf( v.y, dxx, r10.y));
      v = vs[3][n];
      r11.x = fmaf(v.x, sx, fmaf(-v.y, dyy, r11.x));
      r11.y = fmaf(v.x, sy, fmaf( v.y, dxx, r11.y));
    }
    // Woodbury: kf = r00 - r01*r10/(1+r11); then *= 2/(1+omega) = 1 + i*T
    c32 den = make_float2(1.0f + r11.x, r11.y);
    float idn = 1.0f / (den.x*den.x + den.y*den.y);
    c32 invden = make_float2(den.x*idn, -den.y*idn);
    c32 kf = csub(r00, cmul(cmul(r01, r10), invden));
    Xs[j] = make_float2(kf.x - T*kf.y, kf.y + T*kf.x);
  }
  __syncthreads();

  // --- real-irfft packing: Z[k] = (E[k] + i*O[k]) / MF ---
  //   E = (X[k]+conj(X[M-k]))/2 ; O = (X[k]-conj(X[M-k]))/2 * e^{+2pi i k/L}
  const float invM = 1.0f / (float)MF;
  for (int k = tid; k < MF; k += 512) {
    c32 Xk = Xs[k];
    c32 Xm = Xs[MF - k];
    float Ex = 0.5f*(Xk.x + Xm.x), Ey = 0.5f*(Xk.y - Xm.y);
    float Ox = 0.5f*(Xk.x - Xm.x), Oy = 0.5f*(Xk.y + Xm.y);
    double ad = (double)k * (6.28318530717958647692 / 8192.0);
    float cs = (float)cos(ad), sn = (float)sin(ad);
    float Orx = Ox*cs - Oy*sn;
    float Ory = Ox*sn + Oy*cs;
    Zs[k] = make_float2((Ex - Ory)*invM, (Ey + Orx)*invM);
  }
  __syncthreads();

  // --- 12-stage radix-2 Stockham inverse FFT (twiddle sign +) ---
  c32* src = Zs;
  c32* dst = Xs;
  for (int s = 0; s < 12; s++) {
    const int m = 1 << s;
    #pragma unroll
    for (int q = 0; q < 4; q++) {
      int p  = tid + 512*q;          // 0..2047 butterflies
      int kk = p & (m - 1);
      int jm = p - kk;               // j << s
      float ang = (float)jm * 1.5339807878856412e-3f;  // 2*pi/4096
      float sn, cs;
      sincosf(ang, &sn, &cs);
      c32 a = src[p], b = src[p + 2048];
      c32 apb = make_float2(a.x + b.x, a.y + b.y);
      c32 amb = make_float2(a.x - b.x, a.y - b.y);
      c32 t = make_float2(cs*amb.x - sn*amb.y, cs*amb.y + sn*amb.x);
      dst[p + jm]     = apb;
      dst[p + jm + m] = t;
    }
    __syncthreads();
    c32* tswap = src; src = dst; dst = tswap;
  }
  // after 12 stages data is back in Zs (= src); z[m] = (x[2m], x[2m+1])
  #pragma unroll
  for (int q = 0; q < 8; q++) {
    int mi = tid + 512*q;
    out[h*MF + mi] = src[mi];
  }
}

extern "C" void kernel_launch(void* const* d_in, const int* in_sizes, int n_in,
                              void* d_out, int out_size, void* d_ws, size_t ws_size,
                              hipStream_t stream) {
  const float* log_dt = (const float*)d_in[0];
  const float* invwr  = (const float*)d_in[1];
  const float* wimag  = (const float*)d_in[2];
  const float* P      = (const float*)d_in[3];
  const float* B      = (const float*)d_in[4];
  const float* C      = (const float*)d_in[5];
  c32* Ct  = (c32*)d_ws;      // H*32 complex = 64 KB scratch
  c32* out = (c32*)d_out;     // (H, 8192) fp32 viewed as (H, 4096) float2

  ssk_setup<<<HH, 256, 0, stream>>>(log_dt, invwr, wimag, P, C, Ct);
  ssk_kern <<<HH, 512, 0, stream>>>(log_dt, invwr, wimag, P, B, Ct, out);
}

// Round 2
// 150.408 us; speedup vs baseline: 1.1760x; 1.1760x over previous
//
#include <hip/hip_runtime.h>

// SSKernelNPLR: H=256 SSM heads, N=32 (M=64 conj-extended), R=1, CH=1, L=8192.
// Stage A (per-h block, 512 thr): build dA^2 directly in closed form
//   (dA = diag(d) - p u^T  =>  dA^2[r][c] = d_r^2 delta - p_r u_c (d_r + d_c - u.p)),
//   then 12 LDS squarings -> dA^8192, then C_t = (C_ - dA_L^T C_)[:32] -> ws.
// Stage B (per-h block, 1024 thr): Cauchy matvec over 4097 FFT nodes
//   (z = 2i tan(pi j/L)), rank-1 Woodbury, *(1+i tan), then irfft via
//   real-packing + 12-stage Stockham radix-2 inverse FFT (4096) in LDS.

#define HH 256
#define NN 32
#define LL 8192
#define LF 4097   // LL/2 + 1
#define MF 4096   // LL/2

typedef float2 c32;

__device__ __forceinline__ c32 cmul(c32 a, c32 b){ return make_float2(a.x*b.x - a.y*b.y, a.x*b.y + a.y*b.x); }
__device__ __forceinline__ c32 cadd(c32 a, c32 b){ return make_float2(a.x+b.x, a.y+b.y); }
__device__ __forceinline__ c32 csub(c32 a, c32 b){ return make_float2(a.x-b.x, a.y-b.y); }
__device__ __forceinline__ c32 cconjf(c32 a){ return make_float2(a.x, -a.y); }
__device__ __forceinline__ void cmac(c32& acc, c32 a, c32 b){
  acc.x = fmaf(a.x, b.x, fmaf(-a.y, b.y, acc.x));
  acc.y = fmaf(a.x, b.y, fmaf(a.y, b.x, acc.y));
}

// ---------------- Kernel A: dA^L and C_t ----------------
// LDS matrices stored with c32-stride 66 (even -> float4-aligned), viewed as
// float4 with stride 33: float4 idx = r*33 + (c>>1) holds cols (2c',2c'+1).
__global__ __launch_bounds__(512)
void ssk_setup(const float* __restrict__ log_dt, const float* __restrict__ invwr,
               const float* __restrict__ wim, const float* __restrict__ Pin,
               const float* __restrict__ Cin, c32* __restrict__ Ct_ws)
{
  __shared__ __align__(16) float4 bufA4[64*33];
  __shared__ __align__(16) float4 bufB4[64*33];
  __shared__ c32 uvec[64], dvec[64], pvec[64], cful[64];
  __shared__ c32 updot_s;
  const int h = blockIdx.x;
  const int tid = threadIdx.x;

  if (tid < 64) {  // wave 0 does the scalar setup; m = tid, conj half for m>=32
    const int n = tid & 31;
    const bool cj = tid >= 32;
    const float dt = expf(log_dt[h]);
    float wr = -expf(invwr[h*NN + n]);
    float wi = wim[h*NN + n];
    if (cj) wi = -wi;
    const float tdt = 2.0f / dt;
    // D = 1/(2/dt - w); E = 2/dt + w   (on conj-extended w)
    float dr = tdt - wr, di = -wi;
    float invd = 1.0f / (dr*dr + di*di);
    c32 D = make_float2(dr*invd, -di*invd);
    c32 E = make_float2(tdt + wr, wi);
    c32 Pf = make_float2(Pin[(h*NN+n)*2], Pin[(h*NN+n)*2+1]);
    if (cj) Pf.y = -Pf.y;
    c32 Cf = make_float2(Cin[(h*NN+n)*2], Cin[(h*NN+n)*2+1]);
    if (cj) Cf.y = -Cf.y;
    // Rm = 1 + sum_m |Pf|^2 Re(D)
    float rm = (Pf.x*Pf.x + Pf.y*Pf.y) * D.x;
    #pragma unroll
    for (int off = 32; off >= 1; off >>= 1) rm += __shfl_xor(rm, off, 64);
    rm += 1.0f;
    c32 Rc = cmul(cconjf(Pf), D);
    float invrm = 1.0f / rm;
    Rc.x *= invrm; Rc.y *= invrm;
    // RP = sum_m Rc[m]*Pf[m]
    c32 RP = cmul(Rc, Pf);
    #pragma unroll
    for (int off = 32; off >= 1; off >>= 1) {
      RP.x += __shfl_xor(RP.x, off, 64);
      RP.y += __shfl_xor(RP.y, off, 64);
    }
    c32 Q2 = cconjf(Pf);                       // Qc2[m] = conj(P_full[m])
    c32 s  = csub(cmul(Rc, E), cmul(RP, Q2));
    c32 u  = cadd(Q2, s);                      // rank-1 right vector
    c32 dd = cmul(D, E);                       // diagonal
    c32 pp = cmul(D, Pf);                      // rank-1 left vector
    uvec[tid] = u;
    dvec[tid] = dd;
    pvec[tid] = pp;
    cful[tid] = Cf;
    // u.p = sum_m u[m]*p[m]  (plain dot) for the closed-form dA^2
    c32 up = cmul(u, pp);
    #pragma unroll
    for (int off = 32; off >= 1; off >>= 1) {
      up.x += __shfl_xor(up.x, off, 64);
      up.y += __shfl_xor(up.y, off, 64);
    }
    if (tid == 0) updot_s = up;
  }
  __syncthreads();

  // thread tile: rows r0+16i (i<4), cols 2*c0, 2*c0+1
  const int r0 = tid >> 5;   // 0..15
  const int c0 = tid & 31;   // 0..31

  // build dA^2 directly: dA2[r][c] = d_r^2 delta - p_r u_c (d_r + d_c - u.p)
  {
    c32 ud = updot_s;
    #pragma unroll
    for (int i = 0; i < 4; i++) {
      int r = r0 + 16*i;
      c32 pr = pvec[r], dr = dvec[r];
      c32 vv[2];
      #pragma unroll
      for (int j = 0; j < 2; j++) {
        int c = 2*c0 + j;
        c32 f = cadd(dr, csub(dvec[c], ud));
        c32 v = cmul(cmul(pr, uvec[c]), f);
        v.x = -v.x; v.y = -v.y;
        if (r == c) { c32 d2 = cmul(dr, dr); v.x += d2.x; v.y += d2.y; }
        vv[j] = v;
      }
      bufA4[r*33 + c0] = make_float4(vv[0].x, vv[0].y, vv[1].x, vv[1].y);
    }
  }
  __syncthreads();

  // 12 squarings: (dA^2)^(2^12) = dA^8192
  float4* src = bufA4;
  float4* dst = bufB4;
  for (int it = 0; it < 12; it++) {
    c32 acc[4][2];
    #pragma unroll
    for (int i = 0; i < 4; i++) { acc[i][0] = make_float2(0,0); acc[i][1] = make_float2(0,0); }
    #pragma unroll 2
    for (int kh = 0; kh < 32; kh++) {       // k = 2kh, 2kh+1
      float4 a4[4];
      a4[0] = src[(r0     )*33 + kh];
      a4[1] = src[(r0 + 16)*33 + kh];
      a4[2] = src[(r0 + 32)*33 + kh];
      a4[3] = src[(r0 + 48)*33 + kh];
      float4 b0 = src[(2*kh    )*33 + c0];  // row k,   cols 2c0,2c0+1
      float4 b1 = src[(2*kh + 1)*33 + c0];  // row k+1, cols 2c0,2c0+1
      c32 b00 = make_float2(b0.x, b0.y), b01 = make_float2(b0.z, b0.w);
      c32 b10 = make_float2(b1.x, b1.y), b11 = make_float2(b1.z, b1.w);
      #pragma unroll
      for (int i = 0; i < 4; i++) {
        c32 ak0 = make_float2(a4[i].x, a4[i].y);
        c32 ak1 = make_float2(a4[i].z, a4[i].w);
        cmac(acc[i][0], ak0, b00);
        cmac(acc[i][1], ak0, b01);
        cmac(acc[i][0], ak1, b10);
        cmac(acc[i][1], ak1, b11);
      }
    }
    #pragma unroll
    for (int i = 0; i < 4; i++)
      dst[(r0 + 16*i)*33 + c0] = make_float4(acc[i][0].x, acc[i][0].y, acc[i][1].x, acc[i][1].y);
    __syncthreads();
    float4* t = src; src = dst; dst = t;
  }

  // C_t[m] = C_full[m] - sum_n dA_L[n][m] * C_full[n],  m < 32
  if (tid < 32) {
    const c32* srcc = (const c32*)src;
    c32 acc = make_float2(0.0f, 0.0f);
    #pragma unroll 4
    for (int n2 = 0; n2 < 64; n2++) cmac(acc, srcc[n2*66 + tid], cful[n2]);
    Ct_ws[h*NN + tid] = csub(cful[tid], acc);
  }
}

// ---------------- Kernel B: Cauchy + Woodbury + irfft ----------------
__global__ __launch_bounds__(1024)
void ssk_kern(const float* __restrict__ log_dt, const float* __restrict__ invwr,
              const float* __restrict__ wim, const float* __restrict__ Pin,
              const float* __restrict__ Bin, const c32* __restrict__ Ct_ws,
              c32* __restrict__ out)
{
  __shared__ c32 Xs[LF + 1];   // spectrum X[0..4096]; reused as FFT ping buffer
  __shared__ c32 Zs[MF];       // packed complex sequence / FFT pong buffer
  __shared__ c32 wdt_s[NN];
  __shared__ c32 vs[4][NN];    // v00,v01,v10,v11 per n
  const int h = blockIdx.x;
  const int tid = threadIdx.x;

  if (tid < NN) {
    const int n = tid;
    float dt = expf(log_dt[h]);
    float wr = -expf(invwr[h*NN + n]);
    float wi = wim[h*NN + n];
    wdt_s[n] = make_float2(wr*dt, wi*dt);
    c32 Bc = make_float2(Bin[(h*NN+n)*2], Bin[(h*NN+n)*2+1]);
    c32 Pc = make_float2(Pin[(h*NN+n)*2], Pin[(h*NN+n)*2+1]);
    c32 Qc = cconjf(Pc);
    c32 Ct = Ct_ws[h*NN + n];
    c32 v00 = cmul(Bc, Ct), v01 = cmul(Bc, Qc), v10 = cmul(Pc, Ct), v11 = cmul(Pc, Qc);
    vs[0][n] = make_float2(v00.x*dt, v00.y*dt);
    vs[1][n] = make_float2(v01.x*dt, v01.y*dt);
    vs[2][n] = make_float2(v10.x*dt, v10.y*dt);
    vs[3][n] = make_float2(v11.x*dt, v11.y*dt);
  }
  __syncthreads();

  // --- Cauchy sum at z_j = 2i*tan(pi j / L), incl. conjugate pairs ---
  for (int j = tid; j < LF; j += 1024) {
    double phid = (double)j * (3.14159265358979323846 / 8192.0);
    float T = (float)tan(phid);          // huge-but-finite at j=4096: limit is exact
    float t2 = 2.0f * T;                 // z = i*t2
    c32 r00 = {0,0}, r01 = {0,0}, r10 = {0,0}, r11 = {0,0};
    #pragma unroll 4
    for (int n = 0; n < NN; n++) {
      c32 w = wdt_s[n];
      float nr  = -w.x;
      float d1i = t2 - w.y;              // z - w
      float d2i = t2 + w.y;              // z - conj(w)
      float inv1 = 1.0f / fmaf(nr, nr, d1i*d1i);
      float inv2 = 1.0f / fmaf(nr, nr, d2i*d2i);
      float c1x = nr*inv1, c1y = -d1i*inv1;
      float c2x = nr*inv2, c2y = -d2i*inv2;
      float sx = c1x + c2x, dxx = c1x - c2x;
      float sy = c1y + c2y, dyy = c1y - c2y;
      c32 v;
      v = vs[0][n];
      r00.x = fmaf(v.x, sx, fmaf(-v.y, dyy, r00.x));
      r00.y = fmaf(v.x, sy, fmaf( v.y, dxx, r00.y));
      v = vs[1][n];
      r01.x = fmaf(v.x, sx, fmaf(-v.y, dyy, r01.x));
      r01.y = fmaf(v.x, sy, fmaf( v.y, dxx, r01.y));
      v = vs[2][n];
      r10.x = fmaf(v.x, sx, fmaf(-v.y, dyy, r10.x));
      r10.y = fmaf(v.x, sy, fmaf( v.y, dxx, r10.y));
      v = vs[3][n];
      r11.x = fmaf(v.x, sx, fmaf(-v.y, dyy, r11.x));
      r11.y = fmaf(v.x, sy, fmaf( v.y, dxx, r11.y));
    }
    // Woodbury: kf = r00 - r01*r10/(1+r11); then *= 2/(1+omega) = 1 + i*T
    c32 den = make_float2(1.0f + r11.x, r11.y);
    float idn = 1.0f / (den.x*den.x + den.y*den.y);
    c32 invden = make_float2(den.x*idn, -den.y*idn);
    c32 kf = csub(r00, cmul(cmul(r01, r10), invden));
    Xs[j] = make_float2(kf.x - T*kf.y, kf.y + T*kf.x);
  }
  __syncthreads();

  // --- real-irfft packing: Z[k] = (E[k] + i*O[k]) / MF ---
  const float invM = 1.0f / (float)MF;
  for (int k = tid; k < MF; k += 1024) {
    c32 Xk = Xs[k];
    c32 Xm = Xs[MF - k];
    float Ex = 0.5f*(Xk.x + Xm.x), Ey = 0.5f*(Xk.y - Xm.y);
    float Ox = 0.5f*(Xk.x - Xm.x), Oy = 0.5f*(Xk.y + Xm.y);
    double ad = (double)k * (6.28318530717958647692 / 8192.0);
    float cs = (float)cos(ad), sn = (float)sin(ad);
    float Orx = Ox*cs - Oy*sn;
    float Ory = Ox*sn + Oy*cs;
    Zs[k] = make_float2((Ex - Ory)*invM, (Ey + Orx)*invM);
  }
  __syncthreads();

  // --- 12-stage radix-2 Stockham inverse FFT (twiddle sign +) ---
  c32* src = Zs;
  c32* dst = Xs;
  for (int s = 0; s < 12; s++) {
    const int m = 1 << s;
    #pragma unroll
    for (int q = 0; q < 2; q++) {
      int p  = tid + 1024*q;         // 0..2047 butterflies
      int kk = p & (m - 1);
      int jm = p - kk;               // j << s
      float ang = (float)jm * 1.5339807878856412e-3f;  // 2*pi/4096
      float sn, cs;
      sincosf(ang, &sn, &cs);
      c32 a = src[p], b = src[p + 2048];
      c32 apb = make_float2(a.x + b.x, a.y + b.y);
      c32 amb = make_float2(a.x - b.x, a.y - b.y);
      c32 t = make_float2(cs*amb.x - sn*amb.y, cs*amb.y + sn*amb.x);
      dst[p + jm]     = apb;
      dst[p + jm + m] = t;
    }
    __syncthreads();
    c32* tswap = src; src = dst; dst = tswap;
  }
  // after 12 stages data is back in Zs (= src); z[m] = (x[2m], x[2m+1])
  #pragma unroll
  for (int q = 0; q < 4; q++) {
    int mi = tid + 1024*q;
    out[h*MF + mi] = src[mi];
  }
}

extern "C" void kernel_launch(void* const* d_in, const int* in_sizes, int n_in,
                              void* d_out, int out_size, void* d_ws, size_t ws_size,
                              hipStream_t stream) {
  const float* log_dt = (const float*)d_in[0];
  const float* invwr  = (const float*)d_in[1];
  const float* wimag  = (const float*)d_in[2];
  const float* P      = (const float*)d_in[3];
  const float* B      = (const float*)d_in[4];
  const float* C      = (const float*)d_in[5];
  c32* Ct  = (c32*)d_ws;      // H*32 complex = 64 KB scratch
  c32* out = (c32*)d_out;     // (H, 8192) fp32 viewed as (H, 4096) float2

  ssk_setup<<<HH, 512, 0, stream>>>(log_dt, invwr, wimag, P, C, Ct);
  ssk_kern <<<HH, 1024, 0, stream>>>(log_dt, invwr, wimag, P, B, Ct, out);
}

// Round 3
// 115.810 us; speedup vs baseline: 1.5274x; 1.2987x over previous
//
#include <hip/hip_runtime.h>

// SSKernelNPLR: H=256 SSM heads, N=32 (M=64 conj-extended), R=1, CH=1, L=8192.
// Stage A (per-h block, 256 thr): closed-form dA^2 (dA = diag(d) - p u^T =>
//   dA^2 = d^2 delta - p_r u_c (d_r + d_c - u.p)), 7 LDS squarings -> dA^256,
//   then 32 register-resident matvecs v <- (dA^256)^T v (single wave,
//   v_readlane broadcast) -> C_t = (C - v)[:32] -> ws.
// Stage B (per-h block, 1024 thr): Cauchy matvec over 4096 FFT nodes
//   (z = 2i tan(pi j/L), 4 nodes/thread, hw v_sin/v_cos), Nyquist node by
//   analytic limit, rank-1 Woodbury, *(1+i tan), then irfft via real-packing
//   + 12-stage Stockham radix-2 inverse FFT (4096) in LDS.

#define HH 256
#define NN 32
#define LL 8192
#define LF 4097   // LL/2 + 1
#define MF 4096   // LL/2

typedef float2 c32;

__device__ __forceinline__ c32 cmul(c32 a, c32 b){ return make_float2(a.x*b.x - a.y*b.y, a.x*b.y + a.y*b.x); }
__device__ __forceinline__ c32 cadd(c32 a, c32 b){ return make_float2(a.x+b.x, a.y+b.y); }
__device__ __forceinline__ c32 csub(c32 a, c32 b){ return make_float2(a.x-b.x, a.y-b.y); }
__device__ __forceinline__ c32 cconjf(c32 a){ return make_float2(a.x, -a.y); }
__device__ __forceinline__ void cmac(c32& acc, c32 a, c32 b){
  acc.x = fmaf(a.x, b.x, fmaf(-a.y, b.y, acc.x));
  acc.y = fmaf(a.x, b.y, fmaf(a.y, b.x, acc.y));
}
__device__ __forceinline__ float bcast_lane(float v, int n){
  return __int_as_float(__builtin_amdgcn_readlane(__float_as_int(v), n));
}

// ---------------- Kernel A: dA^L and C_t ----------------
// LDS matrices stored with c32-stride 66, viewed as float4 stride 33:
// float4 idx r*33 + f holds cols (2f, 2f+1).
__global__ __launch_bounds__(256)
void ssk_setup(const float* __restrict__ log_dt, const float* __restrict__ invwr,
               const float* __restrict__ wim, const float* __restrict__ Pin,
               const float* __restrict__ Cin, c32* __restrict__ Ct_ws)
{
  __shared__ __align__(16) float4 bufA4[64*33];
  __shared__ __align__(16) float4 bufB4[64*33];
  __shared__ c32 uvec[64], dvec[64], pvec[64], cful[64];
  __shared__ c32 updot_s;
  const int h = blockIdx.x;
  const int tid = threadIdx.x;

  if (tid < 64) {  // wave 0: scalar setup; m = tid, conj half for m>=32
    const int n = tid & 31;
    const bool cj = tid >= 32;
    const float dt = expf(log_dt[h]);
    float wr = -expf(invwr[h*NN + n]);
    float wi = wim[h*NN + n];
    if (cj) wi = -wi;
    const float tdt = 2.0f / dt;
    float dr = tdt - wr, di = -wi;
    float invd = 1.0f / (dr*dr + di*di);
    c32 D = make_float2(dr*invd, -di*invd);      // 1/(2/dt - w)
    c32 E = make_float2(tdt + wr, wi);           // 2/dt + w
    c32 Pf = make_float2(Pin[(h*NN+n)*2], Pin[(h*NN+n)*2+1]);
    if (cj) Pf.y = -Pf.y;
    c32 Cf = make_float2(Cin[(h*NN+n)*2], Cin[(h*NN+n)*2+1]);
    if (cj) Cf.y = -Cf.y;
    float rm = (Pf.x*Pf.x + Pf.y*Pf.y) * D.x;    // Rm = 1 + sum |Pf|^2 Re(D)
    #pragma unroll
    for (int off = 32; off >= 1; off >>= 1) rm += __shfl_xor(rm, off, 64);
    rm += 1.0f;
    c32 Rc = cmul(cconjf(Pf), D);
    float invrm = 1.0f / rm;
    Rc.x *= invrm; Rc.y *= invrm;
    c32 RP = cmul(Rc, Pf);                       // sum_m Rc*Pf
    #pragma unroll
    for (int off = 32; off >= 1; off >>= 1) {
      RP.x += __shfl_xor(RP.x, off, 64);
      RP.y += __shfl_xor(RP.y, off, 64);
    }
    c32 Q2 = cconjf(Pf);
    c32 s  = csub(cmul(Rc, E), cmul(RP, Q2));
    c32 u  = cadd(Q2, s);
    c32 dd = cmul(D, E);
    c32 pp = cmul(D, Pf);
    uvec[tid] = u; dvec[tid] = dd; pvec[tid] = pp; cful[tid] = Cf;
    c32 up = cmul(u, pp);                        // u.p plain dot
    #pragma unroll
    for (int off = 32; off >= 1; off >>= 1) {
      up.x += __shfl_xor(up.x, off, 64);
      up.y += __shfl_xor(up.y, off, 64);
    }
    if (tid == 0) updot_s = up;
  }
  __syncthreads();

  const int r0 = tid >> 4;   // 0..15 (rows r0 + 16i)
  const int c0 = tid & 15;   // 0..15 (cols 2c0,2c0+1,2c0+32,2c0+33)

  // closed-form dA^2
  {
    c32 ud = updot_s;
    #pragma unroll
    for (int i = 0; i < 4; i++) {
      int r = r0 + 16*i;
      c32 pr = pvec[r], dr = dvec[r];
      c32 d2r = cmul(dr, dr);
      #pragma unroll
      for (int jh = 0; jh < 2; jh++) {
        c32 vv[2];
        #pragma unroll
        for (int j = 0; j < 2; j++) {
          int c = 2*c0 + 32*jh + j;
          c32 f = cadd(dr, csub(dvec[c], ud));
          c32 v = cmul(cmul(pr, uvec[c]), f);
          v.x = -v.x; v.y = -v.y;
          if (r == c) { v.x += d2r.x; v.y += d2r.y; }
          vv[j] = v;
        }
        bufA4[r*33 + c0 + 16*jh] = make_float4(vv[0].x, vv[0].y, vv[1].x, vv[1].y);
      }
    }
  }
  __syncthreads();

  // 7 squarings: (dA^2)^(2^7) = dA^256
  float4* src = bufA4;
  float4* dst = bufB4;
  for (int it = 0; it < 7; it++) {
    c32 acc[4][4];
    #pragma unroll
    for (int i = 0; i < 4; i++)
      #pragma unroll
      for (int j = 0; j < 4; j++) acc[i][j] = make_float2(0.0f, 0.0f);
    #pragma unroll 2
    for (int kh = 0; kh < 32; kh++) {       // k = 2kh, 2kh+1
      float4 a4[4];
      a4[0] = src[(r0     )*33 + kh];
      a4[1] = src[(r0 + 16)*33 + kh];
      a4[2] = src[(r0 + 32)*33 + kh];
      a4[3] = src[(r0 + 48)*33 + kh];
      float4 bA0 = src[(2*kh  )*33 + c0     ];   // row k:   cols 2c0,2c0+1
      float4 bA1 = src[(2*kh  )*33 + c0 + 16];   // row k:   cols 2c0+32,+33
      float4 bB0 = src[(2*kh+1)*33 + c0     ];   // row k+1
      float4 bB1 = src[(2*kh+1)*33 + c0 + 16];
      c32 bA0l = make_float2(bA0.x,bA0.y), bA0h = make_float2(bA0.z,bA0.w);
      c32 bA1l = make_float2(bA1.x,bA1.y), bA1h = make_float2(bA1.z,bA1.w);
      c32 bB0l = make_float2(bB0.x,bB0.y), bB0h = make_float2(bB0.z,bB0.w);
      c32 bB1l = make_float2(bB1.x,bB1.y), bB1h = make_float2(bB1.z,bB1.w);
      #pragma unroll
      for (int i = 0; i < 4; i++) {
        c32 ak0 = make_float2(a4[i].x, a4[i].y);
        c32 ak1 = make_float2(a4[i].z, a4[i].w);
        cmac(acc[i][0], ak0, bA0l); cmac(acc[i][1], ak0, bA0h);
        cmac(acc[i][2], ak0, bA1l); cmac(acc[i][3], ak0, bA1h);
        cmac(acc[i][0], ak1, bB0l); cmac(acc[i][1], ak1, bB0h);
        cmac(acc[i][2], ak1, bB1l); cmac(acc[i][3], ak1, bB1h);
      }
    }
    #pragma unroll
    for (int i = 0; i < 4; i++) {
      dst[(r0 + 16*i)*33 + c0     ] = make_float4(acc[i][0].x, acc[i][0].y, acc[i][1].x, acc[i][1].y);
      dst[(r0 + 16*i)*33 + c0 + 16] = make_float4(acc[i][2].x, acc[i][2].y, acc[i][3].x, acc[i][3].y);
    }
    __syncthreads();
    float4* t = src; src = dst; dst = t;
  }

  // tail: v <- X^T v, 32 times (X = dA^256), single wave, X in registers.
  // lane m holds column m of X and v[m]; v[n] broadcast via v_readlane.
  if (tid < 64) {
    const c32* Xl = (const c32*)src;    // c32 stride 66
    c32 Xc[64];
    #pragma unroll
    for (int n = 0; n < 64; n++) Xc[n] = Xl[n*66 + tid];
    c32 v = cful[tid];
    for (int itv = 0; itv < 32; itv++) {
      c32 aa[4];
      #pragma unroll
      for (int a = 0; a < 4; a++) aa[a] = make_float2(0.0f, 0.0f);
      #pragma unroll
      for (int n = 0; n < 64; n++) {
        float sx = bcast_lane(v.x, n);
        float sy = bcast_lane(v.y, n);
        c32 xn = Xc[n];
        aa[n&3].x = fmaf(sx, xn.x, fmaf(-sy, xn.y, aa[n&3].x));
        aa[n&3].y = fmaf(sx, xn.y, fmaf( sy, xn.x, aa[n&3].y));
      }
      v.x = (aa[0].x + aa[1].x) + (aa[2].x + aa[3].x);
      v.y = (aa[0].y + aa[1].y) + (aa[2].y + aa[3].y);
    }
    if (tid < 32) Ct_ws[h*NN + tid] = csub(cful[tid], v);
  }
}

// ---------------- Kernel B: Cauchy + Woodbury + irfft ----------------
__global__ __launch_bounds__(1024)
void ssk_kern(const float* __restrict__ log_dt, const float* __restrict__ invwr,
              const float* __restrict__ wim, const float* __restrict__ Pin,
              const float* __restrict__ Bin, const c32* __restrict__ Ct_ws,
              c32* __restrict__ out)
{
  __shared__ c32 Xs[LF + 1];   // spectrum X[0..4096]; reused as FFT ping buffer
  __shared__ c32 Zs[MF];       // packed complex sequence / FFT pong buffer
  __shared__ c32 wdt_s[NN];
  __shared__ c32 vs[4][NN];    // v00,v01,v10,v11 per n (dt-scaled)
  const int h = blockIdx.x;
  const int tid = threadIdx.x;

  if (tid < NN) {
    const int n = tid;
    float dt = expf(log_dt[h]);
    float wr = -expf(invwr[h*NN + n]);
    float wi = wim[h*NN + n];
    wdt_s[n] = make_float2(wr*dt, wi*dt);
    c32 Bc = make_float2(Bin[(h*NN+n)*2], Bin[(h*NN+n)*2+1]);
    c32 Pc = make_float2(Pin[(h*NN+n)*2], Pin[(h*NN+n)*2+1]);
    c32 Qc = cconjf(Pc);
    c32 Ct = Ct_ws[h*NN + n];
    c32 v00 = cmul(Bc, Ct), v01 = cmul(Bc, Qc), v10 = cmul(Pc, Ct), v11 = cmul(Pc, Qc);
    vs[0][n] = make_float2(v00.x*dt, v00.y*dt);
    vs[1][n] = make_float2(v01.x*dt, v01.y*dt);
    vs[2][n] = make_float2(v10.x*dt, v10.y*dt);
    vs[3][n] = make_float2(v11.x*dt, v11.y*dt);
    // Nyquist node analytic limit: X[4096] = sum_n Re(v00*dt)
    float s00 = v00.x * dt;
    #pragma unroll
    for (int off = 16; off >= 1; off >>= 1) s00 += __shfl_xor(s00, off, 64);
    if (n == 0) Xs[MF] = make_float2(s00, 0.0f);
  }
  __syncthreads();

  // --- Cauchy at z_j = 2i*tan(pi j / L): 4 nodes per thread, j = tid+1024q ---
  {
    float Tq[4], t2[4];
    c32 a00[4], a01[4], a10[4], a11[4];
    #pragma unroll
    for (int q = 0; q < 4; q++) {
      int j = tid + 1024*q;
      float rev = (float)j * (1.0f/16384.0f);       // (pi j/8192) / (2 pi)
      float sn = __builtin_amdgcn_sinf(rev);        // hw: sin(2*pi*rev)
      float cs = __builtin_amdgcn_cosf(rev);        // rev < 0.25 -> cs > 0
      float T = sn / cs;
      Tq[q] = T; t2[q] = 2.0f*T;
      a00[q] = make_float2(0,0); a01[q] = make_float2(0,0);
      a10[q] = make_float2(0,0); a11[q] = make_float2(0,0);
    }
    for (int n = 0; n < NN; n++) {
      c32 w = wdt_s[n];
      float nr  = -w.x;
      float nr2 = nr*nr;
      c32 v0 = vs[0][n], v1 = vs[1][n], v2 = vs[2][n], v3 = vs[3][n];
      #pragma unroll
      for (int q = 0; q < 4; q++) {
        float d1i = t2[q] - w.y;
        float d2i = t2[q] + w.y;
        float inv1 = 1.0f / fmaf(d1i, d1i, nr2);
        float inv2 = 1.0f / fmaf(d2i, d2i, nr2);
        float c1x = nr*inv1, c1y = -d1i*inv1;
        float c2x = nr*inv2, c2y = -d2i*inv2;
        float sx = c1x + c2x, dxx = c1x - c2x;
        float sy = c1y + c2y, dyy = c1y - c2y;
        a00[q].x = fmaf(v0.x, sx, fmaf(-v0.y, dyy, a00[q].x));
        a00[q].y = fmaf(v0.x, sy, fmaf( v0.y, dxx, a00[q].y));
        a01[q].x = fmaf(v1.x, sx, fmaf(-v1.y, dyy, a01[q].x));
        a01[q].y = fmaf(v1.x, sy, fmaf( v1.y, dxx, a01[q].y));
        a10[q].x = fmaf(v2.x, sx, fmaf(-v2.y, dyy, a10[q].x));
        a10[q].y = fmaf(v2.x, sy, fmaf( v2.y, dxx, a10[q].y));
        a11[q].x = fmaf(v3.x, sx, fmaf(-v3.y, dyy, a11[q].x));
        a11[q].y = fmaf(v3.x, sy, fmaf( v3.y, dxx, a11[q].y));
      }
    }
    #pragma unroll
    for (int q = 0; q < 4; q++) {
      c32 den = make_float2(1.0f + a11[q].x, a11[q].y);
      float idn = 1.0f / (den.x*den.x + den.y*den.y);
      c32 invden = make_float2(den.x*idn, -den.y*idn);
      c32 kf = csub(a00[q], cmul(cmul(a01[q], a10[q]), invden));
      float T = Tq[q];
      Xs[tid + 1024*q] = make_float2(kf.x - T*kf.y, kf.y + T*kf.x);  // *(1+iT)
    }
  }
  __syncthreads();

  // --- real-irfft packing: Z[k] = (E[k] + i*O[k]) / MF ---
  const float invM = 1.0f / (float)MF;
  #pragma unroll
  for (int qq = 0; qq < 4; qq++) {
    int k = tid + 1024*qq;
    c32 Xk = Xs[k];
    c32 Xm = Xs[MF - k];
    float Ex = 0.5f*(Xk.x + Xm.x), Ey = 0.5f*(Xk.y - Xm.y);
    float Ox = 0.5f*(Xk.x - Xm.x), Oy = 0.5f*(Xk.y + Xm.y);
    float rev = (float)k * (1.0f/8192.0f);         // 2*pi*k/L in revolutions
    float cs = __builtin_amdgcn_cosf(rev);
    float sn = __builtin_amdgcn_sinf(rev);
    float Orx = Ox*cs - Oy*sn;
    float Ory = Ox*sn + Oy*cs;
    Zs[k] = make_float2((Ex - Ory)*invM, (Ey + Orx)*invM);
  }
  __syncthreads();

  // --- 12-stage radix-2 Stockham inverse FFT (twiddle sign +) ---
  c32* srcf = Zs;
  c32* dstf = Xs;
  for (int s = 0; s < 12; s++) {
    const int m = 1 << s;
    #pragma unroll
    for (int q = 0; q < 2; q++) {
      int p  = tid + 1024*q;         // 0..2047 butterflies
      int kk = p & (m - 1);
      int jm = p - kk;               // j << s
      float rev = (float)jm * (1.0f/4096.0f);
      float sn = __builtin_amdgcn_sinf(rev);
      float cs = __builtin_amdgcn_cosf(rev);
      c32 a = srcf[p], b = srcf[p + 2048];
      c32 apb = make_float2(a.x + b.x, a.y + b.y);
      c32 amb = make_float2(a.x - b.x, a.y - b.y);
      c32 t = make_float2(cs*amb.x - sn*amb.y, cs*amb.y + sn*amb.x);
      dstf[p + jm]     = apb;
      dstf[p + jm + m] = t;
    }
    __syncthreads();
    c32* tswap = srcf; srcf = dstf; dstf = tswap;
  }
  // after 12 stages data is back in Zs (= srcf); z[m] = (x[2m], x[2m+1])
  #pragma unroll
  for (int q = 0; q < 4; q++) {
    int mi = tid + 1024*q;
    out[h*MF + mi] = srcf[mi];
  }
}

extern "C" void kernel_launch(void* const* d_in, const int* in_sizes, int n_in,
                              void* d_out, int out_size, void* d_ws, size_t ws_size,
                              hipStream_t stream) {
  const float* log_dt = (const float*)d_in[0];
  const float* invwr  = (const float*)d_in[1];
  const float* wimag  = (const float*)d_in[2];
  const float* P      = (const float*)d_in[3];
  const float* B      = (const float*)d_in[4];
  const float* C      = (const float*)d_in[5];
  c32* Ct  = (c32*)d_ws;      // H*32 complex = 64 KB scratch
  c32* out = (c32*)d_out;     // (H, 8192) fp32 viewed as (H, 4096) float2

  ssk_setup<<<HH, 256, 0, stream>>>(log_dt, invwr, wimag, P, C, Ct);
  ssk_kern <<<HH, 1024, 0, stream>>>(log_dt, invwr, wimag, P, B, Ct, out);
}

// Round 4
// 78.776 us; speedup vs baseline: 2.2454x; 1.4701x over previous
//
#include <hip/hip_runtime.h>

// SSKernelNPLR fused: H=256, N=32 (M=64 conj-extended), R=1, CH=1, L=8192.
// A: dA^T = diag(d) - u p^T  =>  resolvent via scalar Woodbury; matrix power
//    by spectral sum over 8192-th roots of unity: (dA^T)^L = (1/M) sum_k z_k R(z_k)
//    (z_k^{L+1} = z_k since M = L). Diagonal part taken exactly as d^L.
//    y = C.d^L - u.(1/M) sum_k q_k g(z_k),  q_k = z_k a_k/(1+b_k).
//    Conj-fold: nodes k=0..4096; pair k<->M-k gives q g_lo + conj(q g_hi);
//    self-conj nodes (0, 4096) stored with q *= 0.5.
// B: Cauchy at z_j = 2i tan(pi j/L), rank-1 Woodbury, *(1+iT), real-packed
//    12-stage Stockham inverse FFT (4096) in LDS.  (unchanged, verified)

#define HH 256
#define NN 32
#define LL 8192
#define LF 4097
#define MF 4096

typedef float2 c32;

__device__ __forceinline__ c32 cmul(c32 a, c32 b){ return make_float2(a.x*b.x - a.y*b.y, a.x*b.y + a.y*b.x); }
__device__ __forceinline__ c32 cadd(c32 a, c32 b){ return make_float2(a.x+b.x, a.y+b.y); }
__device__ __forceinline__ c32 csub(c32 a, c32 b){ return make_float2(a.x-b.x, a.y-b.y); }
__device__ __forceinline__ c32 cconjf(c32 a){ return make_float2(a.x, -a.y); }
__device__ __forceinline__ float frcp(float x){ return __builtin_amdgcn_rcpf(x); }

__global__ __launch_bounds__(1024)
void ssk_fused(const float* __restrict__ log_dt, const float* __restrict__ invwr,
               const float* __restrict__ wim, const float* __restrict__ Pin,
               const float* __restrict__ Bin, const float* __restrict__ Cin,
               c32* __restrict__ out)
{
  // big region: contour phase uses qz[4097] float4 (65552 B);
  // FFT phase aliases it as Xs[4098] + Zs[4096] c32 (65552 B).
  __shared__ __align__(16) unsigned char bigbuf[65552];
  __shared__ __align__(16) c32 sPart[64*32];      // 16 KB partials
  __shared__ __align__(16) float4 dpc_s[32];      // (d.x,d.y,pc.x,pc.y)
  __shared__ c32 pu_s[32], u_s[32], C_s[32], dL_s[32], wdt_s[32];
  __shared__ c32 vs[4][32];

  float4* qz = (float4*)bigbuf;
  c32* Xs = (c32*)bigbuf;                          // [0..4097]
  c32* Zs = (c32*)(bigbuf + 4098*sizeof(c32));     // [0..4095]

  const int h = blockIdx.x;
  const int tid = threadIdx.x;

  // ---------------- A1: per-head scalars (wave 0) ----------------
  if (tid < 64) {
    const int n = tid & 31;
    const bool cj = tid >= 32;
    const float dt = expf(log_dt[h]);
    float wr = -expf(invwr[h*NN + n]);
    float wi = wim[h*NN + n];
    if (cj) wi = -wi;
    const float tdt = 2.0f / dt;
    float dr = tdt - wr, di = -wi;
    float invd = 1.0f / (dr*dr + di*di);
    c32 D = make_float2(dr*invd, -di*invd);        // 1/(2/dt - w)
    c32 E = make_float2(tdt + wr, wi);             // 2/dt + w
    c32 Pf = make_float2(Pin[(h*NN+n)*2], Pin[(h*NN+n)*2+1]);
    if (cj) Pf.y = -Pf.y;
    c32 Cf = make_float2(Cin[(h*NN+n)*2], Cin[(h*NN+n)*2+1]);
    if (cj) Cf.y = -Cf.y;
    float rm = (Pf.x*Pf.x + Pf.y*Pf.y) * D.x;      // Rm = 1 + sum |Pf|^2 Re(D)
    #pragma unroll
    for (int off = 32; off >= 1; off >>= 1) rm += __shfl_xor(rm, off, 64);
    rm += 1.0f;
    c32 Rc = cmul(cconjf(Pf), D);
    float invrm = 1.0f / rm;
    Rc.x *= invrm; Rc.y *= invrm;
    c32 RP = cmul(Rc, Pf);
    #pragma unroll
    for (int off = 32; off >= 1; off >>= 1) {
      RP.x += __shfl_xor(RP.x, off, 64);
      RP.y += __shfl_xor(RP.y, off, 64);
    }
    c32 Q2 = cconjf(Pf);
    c32 s  = csub(cmul(Rc, E), cmul(RP, Q2));
    c32 u  = cadd(Q2, s);                          // dA = diag(dd) - pp u^T
    c32 dd = cmul(D, E);
    c32 pp = cmul(D, Pf);
    c32 pc = cmul(pp, Cf);                         // p*C (conj-pair derivable)
    c32 pu = cmul(pp, u);                          // p*u

    // z = -1 node (k=4096): g_hi = conj(g_lo); a,b real = 2 sum Re(pc g_lo)
    float dxx = -1.0f - dd.x;
    float nn1 = fmaf(dxx, dxx, dd.y*dd.y);
    float ii  = frcp(nn1);
    float glx = dxx*ii, gly = dd.y*ii;             // g_lo = conj(-1 - d)/|.|^2
    float aterm = 2.0f*(pc.x*glx - pc.y*gly);
    float bterm = 2.0f*(pu.x*glx - pu.y*gly);
    #pragma unroll
    for (int off = 16; off >= 1; off >>= 1) {
      aterm += __shfl_xor(aterm, off, 64);
      bterm += __shfl_xor(bterm, off, 64);
    }
    if (tid < 32) {
      dpc_s[tid] = make_float4(dd.x, dd.y, pc.x, pc.y);
      pu_s[tid] = pu; u_s[tid] = u; C_s[tid] = Cf;
      wdt_s[tid] = make_float2(wr*dt, wi*dt);
      c32 t = dd;                                  // d^8192 by 13 squarings
      #pragma unroll
      for (int i2 = 0; i2 < 13; i2++) t = cmul(t, t);
      dL_s[tid] = t;
    }
    if (tid == 0) {
      float qn = -aterm * frcp(1.0f + bterm) * 0.5f;  // q(-1), half weight
      qz[4096] = make_float4(-1.0f, 0.0f, qn, 0.0f);
    }
  }
  __syncthreads();

  // ---------------- A2: q_k at z_k = e^{2pi i k/8192}, k = tid + 1024q ----
  {
    float zx4[4], zy4[4];
    c32 a4[4], b4[4];
    #pragma unroll
    for (int q = 0; q < 4; q++) {
      int k = tid + 1024*q;
      float rev = (float)k * (1.0f/8192.0f);
      zx4[q] = __builtin_amdgcn_cosf(rev);
      zy4[q] = __builtin_amdgcn_sinf(rev);
      a4[q] = make_float2(0,0); b4[q] = make_float2(0,0);
    }
    #pragma unroll 2
    for (int m = 0; m < 32; m++) {
      float4 dpc = dpc_s[m];
      c32 pu = pu_s[m];
      #pragma unroll
      for (int q = 0; q < 4; q++) {
        float dxx = zx4[q] - dpc.x;
        float dy1 = zy4[q] - dpc.y;
        float dy2 = zy4[q] + dpc.y;
        float xx  = dxx*dxx;
        float n1  = fmaf(dy1, dy1, xx);
        float n2  = fmaf(dy2, dy2, xx);
        float ip  = frcp(n1*n2);
        float i1  = n2*ip, i2 = n1*ip;
        float glx = dxx*i1, gly = -dy1*i1;          // 1/(z - d)
        float ghx = dxx*i2, ghy = -dy2*i2;          // 1/(z - conj d)
        float sxg = glx+ghx, dxg = glx-ghx, syg = gly+ghy, dyg = gly-ghy;
        a4[q].x = fmaf(dpc.z, sxg, fmaf(-dpc.w, dyg, a4[q].x));
        a4[q].y = fmaf(dpc.z, syg, fmaf( dpc.w, dxg, a4[q].y));
        b4[q].x = fmaf(pu.x, sxg, fmaf(-pu.y, dyg, b4[q].x));
        b4[q].y = fmaf(pu.x, syg, fmaf( pu.y, dxg, b4[q].y));
      }
    }
    #pragma unroll
    for (int q = 0; q < 4; q++) {
      int k = tid + 1024*q;
      float denx = 1.0f + b4[q].x, deny = b4[q].y;
      float idn = frcp(fmaf(denx, denx, deny*deny));
      float tx = (a4[q].x*denx + a4[q].y*deny)*idn;
      float ty = (a4[q].y*denx - a4[q].x*deny)*idn;
      float qx = zx4[q]*tx - zy4[q]*ty;
      float qy = zx4[q]*ty + zy4[q]*tx;
      if (k == 0) { qx *= 0.5f; qy *= 0.5f; }      // self-conj node weight
      qz[k] = make_float4(zx4[q], zy4[q], qx, qy);
    }
  }
  __syncthreads();

  // ---------------- A3: S_m = sum_k q_k g_m + conj(q_k g_{m+32}) ----------
  {
    const int ma = tid & 15, mb = ma + 16;
    const int chunk = tid >> 4;                     // 64 chunks x 64(+1) nodes
    const int kbeg = chunk*64;
    const int kcnt = (chunk == 63) ? 65 : 64;
    float4 da = dpc_s[ma];
    float4 db = dpc_s[mb];
    c32 sa = make_float2(0,0), sb = make_float2(0,0);
    for (int kk = 0; kk < kcnt; kk++) {
      float4 zq = qz[kbeg + kk];                    // zx, zy, qx, qy
      {
        float dxx = zq.x - da.x, dy1 = zq.y - da.y, dy2 = zq.y + da.y;
        float xx = dxx*dxx;
        float n1 = fmaf(dy1,dy1,xx), n2 = fmaf(dy2,dy2,xx);
        float ip = frcp(n1*n2);
        float i1 = n2*ip, i2 = n1*ip;
        float glx = dxx*i1, gly = -dy1*i1;
        float ghx = dxx*i2, ghy = -dy2*i2;
        float sxg = glx+ghx, syg = gly+ghy, dyg = gly-ghy, dxg = glx-ghx;
        sa.x = fmaf(zq.z, sxg, fmaf(-zq.w, syg, sa.x));
        sa.y = fmaf(zq.z, dyg, fmaf( zq.w, dxg, sa.y));
      }
      {
        float dxx = zq.x - db.x, dy1 = zq.y - db.y, dy2 = zq.y + db.y;
        float xx = dxx*dxx;
        float n1 = fmaf(dy1,dy1,xx), n2 = fmaf(dy2,dy2,xx);
        float ip = frcp(n1*n2);
        float i1 = n2*ip, i2 = n1*ip;
        float glx = dxx*i1, gly = -dy1*i1;
        float ghx = dxx*i2, ghy = -dy2*i2;
        float sxg = glx+ghx, syg = gly+ghy, dyg = gly-ghy, dxg = glx-ghx;
        sb.x = fmaf(zq.z, sxg, fmaf(-zq.w, syg, sb.x));
        sb.y = fmaf(zq.z, dyg, fmaf( zq.w, dxg, sb.y));
      }
    }
    sPart[chunk*32 + ma] = sa;
    sPart[chunk*32 + mb] = sb;
  }
  __syncthreads();

  // ------- A4: reduce, C_t, and stage-B v-vectors (lanes 0..31) -----------
  if (tid < 32) {
    const int m = tid;
    c32 S = make_float2(0,0);
    #pragma unroll 8
    for (int c = 0; c < 64; c++) {
      c32 v = sPart[c*32 + m];
      S.x += v.x; S.y += v.y;
    }
    c32 y = cmul(C_s[m], dL_s[m]);                  // exact diagonal part
    c32 uS = cmul(u_s[m], S);
    y.x -= uS.x * (1.0f/8192.0f);
    y.y -= uS.y * (1.0f/8192.0f);
    c32 Ct = csub(C_s[m], y);                       // C~ = C - (dA^L)^T C

    float dt = expf(log_dt[h]);
    c32 Bc = make_float2(Bin[(h*NN+m)*2], Bin[(h*NN+m)*2+1]);
    c32 Pc = make_float2(Pin[(h*NN+m)*2], Pin[(h*NN+m)*2+1]);
    c32 Qc = cconjf(Pc);
    c32 v00 = cmul(Bc, Ct), v01 = cmul(Bc, Qc), v10 = cmul(Pc, Ct), v11 = cmul(Pc, Qc);
    vs[0][m] = make_float2(v00.x*dt, v00.y*dt);
    vs[1][m] = make_float2(v01.x*dt, v01.y*dt);
    vs[2][m] = make_float2(v10.x*dt, v10.y*dt);
    vs[3][m] = make_float2(v11.x*dt, v11.y*dt);
    // Nyquist node of stage B: X[4096] = sum_n Re(v00*dt)
    float s00 = v00.x * dt;
    #pragma unroll
    for (int off = 16; off >= 1; off >>= 1) s00 += __shfl_xor(s00, off, 64);
    if (m == 0) Xs[MF] = make_float2(s00, 0.0f);
  }
  __syncthreads();

  // ------- B1: Cauchy at z_j = 2i tan(pi j/L), 4 nodes/thread -------------
  {
    float Tq[4], t2[4];
    c32 a00[4], a01[4], a10[4], a11[4];
    #pragma unroll
    for (int q = 0; q < 4; q++) {
      int j = tid + 1024*q;
      float rev = (float)j * (1.0f/16384.0f);
      float sn = __builtin_amdgcn_sinf(rev);
      float cs = __builtin_amdgcn_cosf(rev);
      float T = sn * frcp(cs);
      Tq[q] = T; t2[q] = 2.0f*T;
      a00[q] = make_float2(0,0); a01[q] = make_float2(0,0);
      a10[q] = make_float2(0,0); a11[q] = make_float2(0,0);
    }
    for (int n = 0; n < NN; n++) {
      c32 w = wdt_s[n];
      float nr  = -w.x;
      float nr2 = nr*nr;
      c32 v0 = vs[0][n], v1 = vs[1][n], v2 = vs[2][n], v3 = vs[3][n];
      #pragma unroll
      for (int q = 0; q < 4; q++) {
        float d1i = t2[q] - w.y;
        float d2i = t2[q] + w.y;
        float n1 = fmaf(d1i, d1i, nr2);
        float n2 = fmaf(d2i, d2i, nr2);
        float ip = frcp(n1*n2);
        float inv1 = n2*ip, inv2 = n1*ip;
        float c1x = nr*inv1, c1y = -d1i*inv1;
        float c2x = nr*inv2, c2y = -d2i*inv2;
        float sx = c1x + c2x, dxx = c1x - c2x;
        float sy = c1y + c2y, dyy = c1y - c2y;
        a00[q].x = fmaf(v0.x, sx, fmaf(-v0.y, dyy, a00[q].x));
        a00[q].y = fmaf(v0.x, sy, fmaf( v0.y, dxx, a00[q].y));
        a01[q].x = fmaf(v1.x, sx, fmaf(-v1.y, dyy, a01[q].x));
        a01[q].y = fmaf(v1.x, sy, fmaf( v1.y, dxx, a01[q].y));
        a10[q].x = fmaf(v2.x, sx, fmaf(-v2.y, dyy, a10[q].x));
        a10[q].y = fmaf(v2.x, sy, fmaf( v2.y, dxx, a10[q].y));
        a11[q].x = fmaf(v3.x, sx, fmaf(-v3.y, dyy, a11[q].x));
        a11[q].y = fmaf(v3.x, sy, fmaf( v3.y, dxx, a11[q].y));
      }
    }
    #pragma unroll
    for (int q = 0; q < 4; q++) {
      c32 den = make_float2(1.0f + a11[q].x, a11[q].y);
      float idn = 1.0f / (den.x*den.x + den.y*den.y);
      c32 invden = make_float2(den.x*idn, -den.y*idn);
      c32 kf = csub(a00[q], cmul(cmul(a01[q], a10[q]), invden));
      float T = Tq[q];
      Xs[tid + 1024*q] = make_float2(kf.x - T*kf.y, kf.y + T*kf.x);
    }
  }
  __syncthreads();

  // ------- B2: real-irfft packing -----------------------------------------
  const float invM = 1.0f / (float)MF;
  #pragma unroll
  for (int qq = 0; qq < 4; qq++) {
    int k = tid + 1024*qq;
    c32 Xk = Xs[k];
    c32 Xm = Xs[MF - k];
    float Ex = 0.5f*(Xk.x + Xm.x), Ey = 0.5f*(Xk.y - Xm.y);
    float Ox = 0.5f*(Xk.x - Xm.x), Oy = 0.5f*(Xk.y + Xm.y);
    float rev = (float)k * (1.0f/8192.0f);
    float cs = __builtin_amdgcn_cosf(rev);
    float sn = __builtin_amdgcn_sinf(rev);
    float Orx = Ox*cs - Oy*sn;
    float Ory = Ox*sn + Oy*cs;
    Zs[k] = make_float2((Ex - Ory)*invM, (Ey + Orx)*invM);
  }
  __syncthreads();

  // ------- B3: 12-stage radix-2 Stockham inverse FFT ----------------------
  c32* srcf = Zs;
  c32* dstf = Xs;
  for (int s = 0; s < 12; s++) {
    const int m = 1 << s;
    #pragma unroll
    for (int q = 0; q < 2; q++) {
      int p  = tid + 1024*q;
      int kk = p & (m - 1);
      int jm = p - kk;
      float rev = (float)jm * (1.0f/4096.0f);
      float sn = __builtin_amdgcn_sinf(rev);
      float cs = __builtin_amdgcn_cosf(rev);
      c32 a = srcf[p], b = srcf[p + 2048];
      c32 apb = make_float2(a.x + b.x, a.y + b.y);
      c32 amb = make_float2(a.x - b.x, a.y - b.y);
      c32 t = make_float2(cs*amb.x - sn*amb.y, cs*amb.y + sn*amb.x);
      dstf[p + jm]     = apb;
      dstf[p + jm + m] = t;
    }
    __syncthreads();
    c32* tswap = srcf; srcf = dstf; dstf = tswap;
  }
  #pragma unroll
  for (int q = 0; q < 4; q++) {
    int mi = tid + 1024*q;
    out[h*MF + mi] = srcf[mi];
  }
}

extern "C" void kernel_launch(void* const* d_in, const int* in_sizes, int n_in,
                              void* d_out, int out_size, void* d_ws, size_t ws_size,
                              hipStream_t stream) {
  const float* log_dt = (const float*)d_in[0];
  const float* invwr  = (const float*)d_in[1];
  const float* wimag  = (const float*)d_in[2];
  const float* P      = (const float*)d_in[3];
  const float* B      = (const float*)d_in[4];
  const float* C      = (const float*)d_in[5];
  c32* out = (c32*)d_out;     // (H, 8192) fp32 viewed as (H, 4096) float2
  (void)d_ws; (void)ws_size; (void)in_sizes; (void)n_in; (void)out_size;

  ssk_fused<<<HH, 1024, 0, stream>>>(log_dt, invwr, wimag, P, B, C, out);
}